// Round 3
// baseline (1512.206 us; speedup 1.0000x reference)
//
#include <hip/hip_runtime.h>
#include <hip/hip_bf16.h>
#include <cstdint>
#include <math.h>

#define N_EMB   65536
#define N_PROTO 2048
#define DIM     512

// Round 3: latency-bound diagnosis (all pipes <40%) -> remove ALL barriers.
// Each wave owns an independent 64x64 output tile and loads its MFMA A/B
// fragments DIRECTLY from row-major global memory (fragment layout
// A[m=lane&15][k=(lane>>4)*8+j] is 8 contiguous k per lane = two float4),
// converting fp32->bf16 in registers. No LDS, no __syncthreads: every wave
// is a self-paced load->cvt->MFMA pipeline. Row norms fold into the same
// loads (each element seen exactly once per wave), reduced once at the end
// via shfl_xor(16/32). C stores are non-temporal to keep L2/L3 holding A.

typedef __bf16 bf16x8 __attribute__((ext_vector_type(8)));
typedef float  f32x4  __attribute__((ext_vector_type(4)));

__device__ inline bf16x8 cvt8(float4 u, float4 v) {
    bf16x8 r;
    r[0] = (__bf16)u.x; r[1] = (__bf16)u.y; r[2] = (__bf16)u.z; r[3] = (__bf16)u.w;
    r[4] = (__bf16)v.x; r[5] = (__bf16)v.y; r[6] = (__bf16)v.z; r[7] = (__bf16)v.w;
    return r;
}
__device__ inline float dot4(float4 a) { return a.x*a.x + a.y*a.y + a.z*a.z + a.w*a.w; }

// Block 256 = 4 waves in 2x2 (block tile 128x128; A/B lines shared in L1).
// Grid (N_PROTO/128, N_EMB/128), x fastest so 16 consecutive blocks share
// one A row-panel (L2/L3 reuse).
__global__ __launch_bounds__(256, 3) void fused_kernel(const float* __restrict__ E,
                                                       const float* __restrict__ Pm,
                                                       float* __restrict__ out) {
    const int tid   = threadIdx.x;
    const int wave  = tid >> 6, lane = tid & 63;
    const int wm    = wave >> 1, wn = wave & 1;
    const int laneM = lane & 15, laneQ = lane >> 4;

    const int rowBase = blockIdx.y * 128 + wm * 64;   // wave's 64 rows
    const int colBase = blockIdx.x * 128 + wn * 64;   // wave's 64 cols

    // Per-fragment global base pointers: row (base + f*16 + laneM), k-offset laneQ*8.
    const float* pA[4];
    const float* pB[4];
    #pragma unroll
    for (int mi = 0; mi < 4; ++mi)
        pA[mi] = E  + (size_t)(rowBase + mi * 16 + laneM) * DIM + laneQ * 8;
    #pragma unroll
    for (int ni = 0; ni < 4; ++ni)
        pB[ni] = Pm + (size_t)(colBase + ni * 16 + laneM) * DIM + laneQ * 8;

    f32x4 acc[4][4] = {};
    float nA[4] = {0.f, 0.f, 0.f, 0.f};   // partial ||row||^2 (this lane's k-slices)
    float nB[4] = {0.f, 0.f, 0.f, 0.f};   // partial ||col||^2

    for (int kt = 0; kt < DIM / 32; ++kt) {
        const int ko = kt * 32;
        bf16x8 af[4], bfr[4];
        #pragma unroll
        for (int mi = 0; mi < 4; ++mi) {
            const float4 u = *(const float4*)(pA[mi] + ko);
            const float4 v = *(const float4*)(pA[mi] + ko + 4);
            nA[mi] += dot4(u) + dot4(v);
            af[mi] = cvt8(u, v);
        }
        #pragma unroll
        for (int ni = 0; ni < 4; ++ni) {
            const float4 u = *(const float4*)(pB[ni] + ko);
            const float4 v = *(const float4*)(pB[ni] + ko + 4);
            nB[ni] += dot4(u) + dot4(v);
            bfr[ni] = cvt8(u, v);
        }
        #pragma unroll
        for (int mi = 0; mi < 4; ++mi)
            #pragma unroll
            for (int ni = 0; ni < 4; ++ni)
                acc[mi][ni] = __builtin_amdgcn_mfma_f32_16x16x32_bf16(af[mi], bfr[ni], acc[mi][ni], 0, 0, 0);
    }

    // Finish norms: lanes {laneM, laneM+16, laneM+32, laneM+48} hold the four
    // k-slices of the same row/col -> butterfly over bits 4,5. Afterwards every
    // lane holds the full norm of row/col (frag*16 + laneM).
    #pragma unroll
    for (int i = 0; i < 4; ++i) {
        nA[i] += __shfl_xor(nA[i], 16); nA[i] += __shfl_xor(nA[i], 32);
        nB[i] += __shfl_xor(nB[i], 16); nB[i] += __shfl_xor(nB[i], 32);
    }

    // Epilogue. C/D layout: col = lane&15, row = laneQ*4 + reg (m89-verified).
    // Row norm for C-row laneQ*4+r lives at any lane with laneM==laneQ*4+r.
    #pragma unroll
    for (int mi = 0; mi < 4; ++mi) {
        float xs[4];
        #pragma unroll
        for (int r = 0; r < 4; ++r) xs[r] = __shfl(nA[mi], laneQ * 4 + r);
        #pragma unroll
        for (int ni = 0; ni < 4; ++ni) {
            const float pq = nB[ni];          // col = ni*16+laneM: lane-local
            float* o = out + (size_t)(rowBase + mi * 16 + laneQ * 4) * N_PROTO
                           + (colBase + ni * 16 + laneM);
            const f32x4 c = acc[mi][ni];
            __builtin_nontemporal_store(-sqrtf(fmaxf(xs[0] - 2.0f * c[0] + pq, 0.0f)), o + 0 * (size_t)N_PROTO);
            __builtin_nontemporal_store(-sqrtf(fmaxf(xs[1] - 2.0f * c[1] + pq, 0.0f)), o + 1 * (size_t)N_PROTO);
            __builtin_nontemporal_store(-sqrtf(fmaxf(xs[2] - 2.0f * c[2] + pq, 0.0f)), o + 2 * (size_t)N_PROTO);
            __builtin_nontemporal_store(-sqrtf(fmaxf(xs[3] - 2.0f * c[3] + pq, 0.0f)), o + 3 * (size_t)N_PROTO);
        }
    }
}

extern "C" void kernel_launch(void* const* d_in, const int* in_sizes, int n_in,
                              void* d_out, int out_size, void* d_ws, size_t ws_size,
                              hipStream_t stream) {
    const float* emb = (const float*)d_in[0];
    const float* pro = (const float*)d_in[1];
    float* out = (float*)d_out;
    (void)d_ws; (void)ws_size; (void)in_sizes; (void)n_in; (void)out_size;

    fused_kernel<<<dim3(N_PROTO / 128, N_EMB / 128), 256, 0, stream>>>(emb, pro, out);
}